// Round 1
// baseline (1013.554 us; speedup 1.0000x reference)
//
#include <hip/hip_runtime.h>
#include <hip/hip_bf16.h>
#include <math.h>

#define B_ 2
#define L_ 2048
#define D_ 2048
#define H_ 16
#define HD_ 128
#define E_ (B_*L_*D_)   // 8388608
#define W_ (D_*D_)      // 4194304

typedef __bf16 bf16;
typedef __bf16 bf16x8 __attribute__((ext_vector_type(8)));
typedef __bf16 bf16x4 __attribute__((ext_vector_type(4)));
typedef float  f32x4  __attribute__((ext_vector_type(4)));

// ---------------- f32 -> bf16 convert ----------------
__global__ void cvt_f32_bf16(const float* __restrict__ src, bf16* __restrict__ dst, int n) {
  int i = (blockIdx.x * blockDim.x + threadIdx.x) * 4;
  if (i + 3 < n) {
    f32x4 v = *reinterpret_cast<const f32x4*>(src + i);
    bf16x4 o;
    o[0] = (bf16)v[0]; o[1] = (bf16)v[1]; o[2] = (bf16)v[2]; o[3] = (bf16)v[3];
    *reinterpret_cast<bf16x4*>(dst + i) = o;
  }
}

// ---------------- RoPE cos/sin table: [L][64] ----------------
__global__ void rope_table(float* __restrict__ ct, float* __restrict__ st) {
  int t = blockIdx.x;      // position
  int i = threadIdx.x;     // pair index < 64
  float inv = powf(10000.0f, -2.0f * (float)i / 128.0f);
  float f = (float)t * inv;
  ct[t * 64 + i] = cosf(f);
  st[t * 64 + i] = sinf(f);
}

// ---------------- in-place RoPE on Q and K (bf16, layout (b,l,h*128+d)) ----------------
__global__ void rope_inplace(bf16* __restrict__ Q, bf16* __restrict__ Kt,
                             const float* __restrict__ ct, const float* __restrict__ st) {
  size_t idx = (size_t)blockIdx.x * blockDim.x + threadIdx.x;  // 2*E/8 threads
  const size_t per = E_ / 8;
  bf16* P = (idx < per) ? Q : Kt;
  size_t li = ((idx < per) ? idx : idx - per) * 8;   // element index, 8 elems = 4 pairs
  int l   = (int)((li / D_) % L_);
  int col = (int)(li % D_);
  int i0  = (col & 127) >> 1;                        // first pair index (mult of 4)
  bf16x8 v = *reinterpret_cast<const bf16x8*>(P + li);
  f32x4 c4 = *reinterpret_cast<const f32x4*>(ct + l * 64 + i0);
  f32x4 s4 = *reinterpret_cast<const f32x4*>(st + l * 64 + i0);
  bf16x8 o;
#pragma unroll
  for (int p = 0; p < 4; ++p) {
    float x1 = (float)v[2*p], x2 = (float)v[2*p+1];
    o[2*p]   = (bf16)(x1 * c4[p] - x2 * s4[p]);
    o[2*p+1] = (bf16)(x1 * s4[p] + x2 * c4[p]);
  }
  *reinterpret_cast<bf16x8*>(P + li) = o;
}

// ---------------- V (b,l,h*128+d) -> Vt (b,h,d,l) tiled transpose ----------------
__global__ void transpose_v(const bf16* __restrict__ Vraw, bf16* __restrict__ Vt) {
  __shared__ bf16 tile[32][33];
  int bh = blockIdx.z; int b = bh >> 4, h = bh & 15;
  int l0 = blockIdx.x * 32, d0 = blockIdx.y * 32;
  int tx = threadIdx.x, ty = threadIdx.y;   // (32,8)
#pragma unroll
  for (int j = 0; j < 4; ++j) {
    int r = ty + j * 8;
    tile[r][tx] = Vraw[((size_t)b * L_ + l0 + r) * D_ + h * HD_ + d0 + tx];
  }
  __syncthreads();
#pragma unroll
  for (int j = 0; j < 4; ++j) {
    int r = ty + j * 8;
    Vt[((size_t)bh * HD_ + d0 + r) * L_ + l0 + tx] = tile[tx][r];
  }
}

// ---------------- zero strictly-upper (tile-granular) part of attn ----------------
__global__ void zero_upper(float* __restrict__ attn) {
  int l = blockIdx.x, bh = blockIdx.y;
  int z0 = ((l >> 4) + 1) << 4;
  float* row = attn + ((size_t)bh * L_ + l) * L_;
  for (int c = z0 + threadIdx.x * 4; c < L_; c += 256 * 4) {
    *reinterpret_cast<f32x4*>(row + c) = (f32x4){0.f, 0.f, 0.f, 0.f};
  }
}

// ---------------- GEMM: C[M,N] = A[M,K] @ Bw[N,K]^T  (bf16 in, f32 acc) ----------------
template<int OUT_BF16>
__global__ __launch_bounds__(256) void gemm_bt(const bf16* __restrict__ A,
                                               const bf16* __restrict__ Bw,
                                               void* __restrict__ Cout,
                                               int M, int N, int K) {
  __shared__ bf16 As[128][72];   // +8 pad: conflict-free ds_read_b128
  __shared__ bf16 Bs[128][72];
  const int tid = threadIdx.x;
  const int lane = tid & 63;
  const int w = tid >> 6;
  const int l15 = lane & 15, g = lane >> 4;
  const int m0 = blockIdx.y * 128, n0 = blockIdx.x * 128;
  const int wm = (w >> 1) * 64, wn = (w & 1) * 64;

  f32x4 acc[4][4];
#pragma unroll
  for (int m = 0; m < 4; ++m)
#pragma unroll
    for (int n = 0; n < 4; ++n) acc[m][n] = (f32x4){0.f, 0.f, 0.f, 0.f};

  for (int kt = 0; kt < K; kt += 64) {
    bf16x8 ra[4], rb[4];
#pragma unroll
    for (int i = 0; i < 4; ++i) {
      int chunk = tid + 256 * i;          // 1024 chunks of 8 bf16
      int row = chunk >> 3, c8 = (chunk & 7) * 8;
      ra[i] = *reinterpret_cast<const bf16x8*>(A  + (size_t)(m0 + row) * K + kt + c8);
      rb[i] = *reinterpret_cast<const bf16x8*>(Bw + (size_t)(n0 + row) * K + kt + c8);
    }
    __syncthreads();   // previous iteration's reads done
#pragma unroll
    for (int i = 0; i < 4; ++i) {
      int chunk = tid + 256 * i;
      int row = chunk >> 3, c8 = (chunk & 7) * 8;
      *reinterpret_cast<bf16x8*>(&As[row][c8]) = ra[i];
      *reinterpret_cast<bf16x8*>(&Bs[row][c8]) = rb[i];
    }
    __syncthreads();
#pragma unroll
    for (int kk = 0; kk < 64; kk += 32) {
      bf16x8 af[4], bfr[4];
#pragma unroll
      for (int m = 0; m < 4; ++m)
        af[m] = *reinterpret_cast<const bf16x8*>(&As[wm + m * 16 + l15][kk + g * 8]);
#pragma unroll
      for (int n = 0; n < 4; ++n)
        bfr[n] = *reinterpret_cast<const bf16x8*>(&Bs[wn + n * 16 + l15][kk + g * 8]);
#pragma unroll
      for (int m = 0; m < 4; ++m)
#pragma unroll
        for (int n = 0; n < 4; ++n)
          acc[m][n] = __builtin_amdgcn_mfma_f32_16x16x32_bf16(af[m], bfr[n], acc[m][n], 0, 0, 0);
    }
  }
  // epilogue: D row=(lane>>4)*4+reg, col=lane&15
#pragma unroll
  for (int m = 0; m < 4; ++m) {
    int row = m0 + wm + m * 16 + g * 4;
#pragma unroll
    for (int n = 0; n < 4; ++n) {
      int col = n0 + wn + n * 16 + l15;
#pragma unroll
      for (int r = 0; r < 4; ++r) {
        if (OUT_BF16) ((bf16*)Cout)[(size_t)(row + r) * N + col] = (bf16)acc[m][n][r];
        else          ((float*)Cout)[(size_t)(row + r) * N + col] = acc[m][n][r];
      }
    }
  }
}

// ---------------- fused causal attention ----------------
// grid (L/64, B*H), block 256 (4 waves, each owns a 16-row q tile)
__global__ __launch_bounds__(256) void attn_fused(const bf16* __restrict__ Qb,
                                                  const bf16* __restrict__ Kb,
                                                  const bf16* __restrict__ Vt,
                                                  float* __restrict__ attn,
                                                  bf16* __restrict__ Oh) {
  __shared__ bf16 Plds[4][16][40];   // per-wave P chunk (16 q x 32 k), +8 pad
  const int tid = threadIdx.x;
  const int w = tid >> 6, lane = tid & 63;
  const int l15 = lane & 15, g = lane >> 4;
  const int bh = blockIdx.y, b = bh >> 4, h = bh & 15;
  const int q0 = blockIdx.x * 64 + w * 16;
  const float scale = 0.08838834764831845f;   // 1/sqrt(128)

  const bf16* qrow = Qb + ((size_t)b * L_ + q0 + l15) * D_ + h * HD_;
  bf16x8 qf[4];
#pragma unroll
  for (int c = 0; c < 4; ++c)
    qf[c] = *reinterpret_cast<const bf16x8*>(qrow + c * 32 + g * 8);

  float m[4]   = {-1e30f, -1e30f, -1e30f, -1e30f};
  float sum[4] = {0.f, 0.f, 0.f, 0.f};
  const bf16* kbase = Kb + ((size_t)b * L_) * D_ + h * HD_;
  const int ntiles = q0 / 16 + 1;

  // ---- pass 1: row max + sum ----
  for (int t = 0; t < ntiles; ++t) {
    int k0 = t * 16;
    f32x4 acc = (f32x4){0.f, 0.f, 0.f, 0.f};
    const bf16* krow = kbase + (size_t)(k0 + l15) * D_;
#pragma unroll
    for (int c = 0; c < 4; ++c) {
      bf16x8 kf = *reinterpret_cast<const bf16x8*>(krow + c * 32 + g * 8);
      acc = __builtin_amdgcn_mfma_f32_16x16x32_bf16(qf[c], kf, acc, 0, 0, 0);
    }
#pragma unroll
    for (int r = 0; r < 4; ++r) {
      int qr = q0 + g * 4 + r;
      int kcol = k0 + l15;
      float sv = (kcol <= qr) ? acc[r] * scale : -1e30f;
      float tm = sv;
#pragma unroll
      for (int sh = 1; sh < 16; sh <<= 1)
        tm = fmaxf(tm, __shfl_xor(tm, sh, 64));
      float mn = fmaxf(m[r], tm);
      float e = __expf(sv - mn);
      float ts = e;
#pragma unroll
      for (int sh = 1; sh < 16; sh <<= 1)
        ts += __shfl_xor(ts, sh, 64);
      sum[r] = sum[r] * __expf(m[r] - mn) + ts;
      m[r] = mn;
    }
  }

  float rinv[4];
#pragma unroll
  for (int r = 0; r < 4; ++r) rinv[r] = 1.0f / sum[r];

  f32x4 oacc[8];
#pragma unroll
  for (int t8 = 0; t8 < 8; ++t8) oacc[t8] = (f32x4){0.f, 0.f, 0.f, 0.f};

  float* arow = attn + ((size_t)bh * L_ + q0) * L_;
  const bf16* vbase = Vt + (size_t)bh * HD_ * L_;
  const int nchunks = (ntiles + 1) >> 1;

  // ---- pass 2: recompute S, write normalized P, accumulate PV ----
  for (int ch = 0; ch < nchunks; ++ch) {
#pragma unroll
    for (int half = 0; half < 2; ++half) {
      int t = ch * 2 + half;
      if (t < ntiles) {
        int k0 = t * 16;
        f32x4 acc = (f32x4){0.f, 0.f, 0.f, 0.f};
        const bf16* krow = kbase + (size_t)(k0 + l15) * D_;
#pragma unroll
        for (int c = 0; c < 4; ++c) {
          bf16x8 kf = *reinterpret_cast<const bf16x8*>(krow + c * 32 + g * 8);
          acc = __builtin_amdgcn_mfma_f32_16x16x32_bf16(qf[c], kf, acc, 0, 0, 0);
        }
#pragma unroll
        for (int r = 0; r < 4; ++r) {
          int qr = q0 + g * 4 + r;
          int kcol = k0 + l15;
          float p = (kcol <= qr) ? __expf(acc[r] * scale - m[r]) * rinv[r] : 0.f;
          arow[(size_t)(g * 4 + r) * L_ + k0 + l15] = p;
          Plds[w][g * 4 + r][half * 16 + l15] = (bf16)p;
        }
      } else {
#pragma unroll
        for (int r = 0; r < 4; ++r)
          Plds[w][g * 4 + r][half * 16 + l15] = (bf16)0.f;
      }
    }
    asm volatile("s_waitcnt lgkmcnt(0)" ::: "memory");
    bf16x8 pa = *reinterpret_cast<const bf16x8*>(&Plds[w][l15][g * 8]);
#pragma unroll
    for (int t8 = 0; t8 < 8; ++t8) {
      const bf16* vrow = vbase + (size_t)(t8 * 16 + l15) * L_ + ch * 32 + g * 8;
      bf16x8 vf = *reinterpret_cast<const bf16x8*>(vrow);
      oacc[t8] = __builtin_amdgcn_mfma_f32_16x16x32_bf16(pa, vf, oacc[t8], 0, 0, 0);
    }
    asm volatile("s_waitcnt lgkmcnt(0)" ::: "memory");  // pa read done before next chunk's writes
  }

  bf16* orow = Oh + ((size_t)b * L_ + q0) * D_ + h * HD_;
#pragma unroll
  for (int t8 = 0; t8 < 8; ++t8)
#pragma unroll
    for (int r = 0; r < 4; ++r)
      orow[(size_t)(g * 4 + r) * D_ + t8 * 16 + l15] = (bf16)oacc[t8][r];
}

// ---------------- host ----------------
extern "C" void kernel_launch(void* const* d_in, const int* in_sizes, int n_in,
                              void* d_out, int out_size, void* d_ws, size_t ws_size,
                              hipStream_t stream) {
  const float* x_q  = (const float*)d_in[0];
  const float* x_kv = (const float*)d_in[1];
  // d_in[2] = attn_mask (causal, -1e9) -- handled analytically
  const float* w_q = (const float*)d_in[3];
  const float* w_k = (const float*)d_in[4];
  const float* w_v = (const float*)d_in[5];
  const float* w_o = (const float*)d_in[6];

  char* p = (char*)d_ws;
  auto alloc = [&](size_t bytes) { char* r = p; p += (bytes + 255) & ~(size_t)255; return r; };
  bf16* xq_b  = (bf16*)alloc((size_t)E_ * 2);
  bf16* xkv_b = (bf16*)alloc((size_t)E_ * 2);
  bf16* wq_b  = (bf16*)alloc((size_t)W_ * 2);
  bf16* wk_b  = (bf16*)alloc((size_t)W_ * 2);
  bf16* wv_b  = (bf16*)alloc((size_t)W_ * 2);
  bf16* wo_b  = (bf16*)alloc((size_t)W_ * 2);
  bf16* Qraw  = (bf16*)alloc((size_t)E_ * 2);
  bf16* Kraw  = (bf16*)alloc((size_t)E_ * 2);
  bf16* Vraw  = (bf16*)alloc((size_t)E_ * 2);
  bf16* Vt    = (bf16*)alloc((size_t)E_ * 2);
  bf16* Oh    = (bf16*)alloc((size_t)E_ * 2);
  float* ct   = (float*)alloc((size_t)L_ * 64 * 4);
  float* st2  = (float*)alloc((size_t)L_ * 64 * 4);

  float* out0     = (float*)d_out;
  float* attn_out = out0 + E_;

  cvt_f32_bf16<<<8192, 256, 0, stream>>>(x_q,  xq_b,  E_);
  cvt_f32_bf16<<<8192, 256, 0, stream>>>(x_kv, xkv_b, E_);
  cvt_f32_bf16<<<4096, 256, 0, stream>>>(w_q, wq_b, W_);
  cvt_f32_bf16<<<4096, 256, 0, stream>>>(w_k, wk_b, W_);
  cvt_f32_bf16<<<4096, 256, 0, stream>>>(w_v, wv_b, W_);
  cvt_f32_bf16<<<4096, 256, 0, stream>>>(w_o, wo_b, W_);
  rope_table<<<L_, 64, 0, stream>>>(ct, st2);

  gemm_bt<1><<<dim3(16, 32), 256, 0, stream>>>(xq_b,  wq_b, Qraw, B_*L_, D_, D_);
  gemm_bt<1><<<dim3(16, 32), 256, 0, stream>>>(xkv_b, wk_b, Kraw, B_*L_, D_, D_);
  gemm_bt<1><<<dim3(16, 32), 256, 0, stream>>>(xkv_b, wv_b, Vraw, B_*L_, D_, D_);

  rope_inplace<<<8192, 256, 0, stream>>>(Qraw, Kraw, ct, st2);
  transpose_v<<<dim3(64, 4, 32), dim3(32, 8), 0, stream>>>(Vraw, Vt);
  zero_upper<<<dim3(2048, 32), 256, 0, stream>>>(attn_out);
  attn_fused<<<dim3(32, 32), 256, 0, stream>>>(Qraw, Kraw, Vt, attn_out, Oh);
  gemm_bt<0><<<dim3(16, 32), 256, 0, stream>>>(Oh, wo_b, out0, B_*L_, D_, D_);
}